// Round 1
// baseline (1396.510 us; speedup 1.0000x reference)
//
#include <hip/hip_runtime.h>

typedef __attribute__((ext_vector_type(8))) short short8;
typedef __attribute__((ext_vector_type(4))) float f32x4;
typedef __attribute__((ext_vector_type(4))) unsigned short ushort4v;

#define DEV __device__ __forceinline__

DEV unsigned short f2bf(float f) {
  unsigned int u = __float_as_uint(f);
  u += 0x7fffu + ((u >> 16) & 1u);
  return (unsigned short)(u >> 16);
}
DEV float sigm(float x) { return 1.f / (1.f + __expf(-x)); }
DEV float tanh_(float x) { return 1.f - 2.f / (1.f + __expf(2.f * x)); }

typedef __attribute__((address_space(1))) const void* as1cv;
typedef __attribute__((address_space(3))) void* as3v;
DEV void gll16(const void* g, void* l) {
  __builtin_amdgcn_global_load_lds((as1cv)g, (as3v)l, 16, 0, 0);
}

// ---------------- sort (stable desc argsort of lengths) + gathers ----------------
__global__ void __launch_bounds__(256) k_sort(const float* __restrict__ x,
    const int* __restrict__ ptar, const int* __restrict__ tlen,
    int* __restrict__ sidx, int* __restrict__ lens, int* __restrict__ tok,
    float* __restrict__ xs, float* __restrict__ tail) {
  __shared__ int ss[64];
  int tid = threadIdx.x;
  if (tid < 64) {
    int li = tlen[tid];
    int rank = 0;
    for (int j = 0; j < 64; ++j) {
      int lj = tlen[j];
      rank += (lj > li || (lj == li && j < tid)) ? 1 : 0;
    }
    ss[rank] = tid;
  }
  __syncthreads();
  if (tid < 64) {
    int src = ss[tid];
    sidx[tid] = src;
    lens[tid] = tlen[src] - 1;
    tail[tid] = (float)src;  // sorted_indices output (as float)
  }
  __syncthreads();
  for (int idx = tid; idx < 32 * 64; idx += 256) {
    int t = idx >> 6, b = idx & 63;
    tok[idx] = ptar[ss[b] * 33 + t];
  }
  for (int idx = tid; idx < 64 * 512; idx += 256) {
    int b = idx >> 9;
    xs[idx] = x[ss[b] * 512 + (idx & 511)];
  }
}

// ---------------- tiled transpose: in[R][C] -> out[C][R] (R,C multiples of 32) ---
__global__ void __launch_bounds__(256) k_transpose(const float* __restrict__ in,
    float* __restrict__ out, int R, int C) {
  __shared__ float tile[32][33];
  int c0 = blockIdx.x * 32, r0 = blockIdx.y * 32;
  int tx = threadIdx.x & 31, ty = threadIdx.x >> 5;
  for (int i = ty; i < 32; i += 8)
    tile[i][tx] = in[(size_t)(r0 + i) * C + (c0 + tx)];
  __syncthreads();
  for (int i = ty; i < 32; i += 8)
    out[(size_t)(c0 + i) * R + (r0 + tx)] = tile[tx][i];
}

// ---------------- h0 = xs @ W_h0^T + b_h0 ; c0 likewise ------------------------
__global__ void __launch_bounds__(512) k_init_hc(const float* __restrict__ xs,
    const float* __restrict__ W_h0, const float* __restrict__ b_h0,
    const float* __restrict__ W_c0, const float* __restrict__ b_c0,
    float* __restrict__ h, float* __restrict__ c) {
  int b = blockIdx.x, u = threadIdx.x;
  __shared__ float xsl[512];
  xsl[u] = xs[b * 512 + u];
  __syncthreads();
  const float4* wh = (const float4*)(W_h0 + (size_t)u * 512);
  const float4* wc = (const float4*)(W_c0 + (size_t)u * 512);
  const float4* xv = (const float4*)xsl;
  float ah = 0.f, ac = 0.f;
#pragma unroll 4
  for (int k4 = 0; k4 < 128; ++k4) {
    float4 xq = xv[k4];
    float4 w1 = wh[k4], w2 = wc[k4];
    ah += xq.x * w1.x + xq.y * w1.y + xq.z * w1.z + xq.w * w1.w;
    ac += xq.x * w2.x + xq.y * w2.y + xq.z * w2.z + xq.w * w2.w;
  }
  h[b * 512 + u] = ah + b_h0[u];
  c[b * 512 + u] = ac + b_c0[u];
}

// ---------------- gx[b][j] = xs[b] . W_ih[j, :512] + b_ih[j] + b_hh[j] ----------
__global__ void __launch_bounds__(256) k_gx(const float* __restrict__ xs,
    const float* __restrict__ W_ihT, const float* __restrict__ b_ih,
    const float* __restrict__ b_hh, float* __restrict__ gx) {
  int b = blockIdx.y;
  int j = blockIdx.x * 256 + threadIdx.x;
  __shared__ float xsl[512];
  for (int k = threadIdx.x; k < 512; k += 256) xsl[k] = xs[b * 512 + k];
  __syncthreads();
  float acc = b_ih[j] + b_hh[j];
#pragma unroll 8
  for (int k = 0; k < 512; ++k) acc += xsl[k] * W_ihT[(size_t)k * 2048 + j];
  gx[b * 2048 + j] = acc;
}

// ---- GA[m][j] = embed[tok[m]] . W_ih[j, 512:768] + gx[b][j]  (m = t*64+b) ------
__global__ void __launch_bounds__(256) k_ga(const int* __restrict__ tok,
    const float* __restrict__ embed, const float* __restrict__ W_ihT,
    const float* __restrict__ gx, float* __restrict__ GA) {
  int j = blockIdx.x * 256 + threadIdx.x;
  int m0 = blockIdx.y * 16;
  __shared__ float E[16][256];
  for (int idx = threadIdx.x; idx < 16 * 256; idx += 256) {
    int mi = idx >> 8;
    E[mi][idx & 255] = embed[(size_t)tok[m0 + mi] * 256 + (idx & 255)];
  }
  __syncthreads();
  float acc[16];
#pragma unroll
  for (int i = 0; i < 16; ++i) acc[i] = 0.f;
  const float* Wp = W_ihT + (size_t)512 * 2048 + j;
#pragma unroll 4
  for (int k = 0; k < 256; ++k) {
    float wv = Wp[(size_t)k * 2048];
#pragma unroll
    for (int i = 0; i < 16; ++i) acc[i] += E[i][k] * wv;
  }
#pragma unroll
  for (int i = 0; i < 16; ++i) {
    int m = m0 + i;
    GA[(size_t)m * 2048 + j] = acc[i] + gx[(m & 63) * 2048 + j];
  }
}

// ---------------- one LSTM step (f32), ping-pong h buffers ----------------------
__global__ void __launch_bounds__(256) k_step(const float* __restrict__ hin,
    float* __restrict__ hout, float* __restrict__ c, const float* __restrict__ GA,
    const float* __restrict__ W_hhT, const int* __restrict__ lens,
    unsigned short* __restrict__ Hm, int t) {
  int u = blockIdx.x * 64 + (threadIdx.x & 63);
  int b = blockIdx.y * 4 + (threadIdx.x >> 6);
  const float* ga = GA + (size_t)(t * 64 + b) * 2048;
  float ai = ga[u], af = ga[512 + u], ag = ga[1024 + u], ao = ga[1536 + u];
  const float* hrow = hin + b * 512;
  const float* W = W_hhT + u;
#pragma unroll 8
  for (int k = 0; k < 512; ++k) {
    float hv = hrow[k];
    const float* wr = W + (size_t)k * 2048;
    ai += hv * wr[0];
    af += hv * wr[512];
    ag += hv * wr[1024];
    ao += hv * wr[1536];
  }
  float cv = c[b * 512 + u];
  float cn = sigm(af) * cv + sigm(ai) * tanh_(ag);
  float hn = sigm(ao) * tanh_(cn);
  bool act = lens[b] > t;
  hout[b * 512 + u] = act ? hn : hrow[u];
  if (act) c[b * 512 + u] = cn;
  Hm[(size_t)(t * 64 + b) * 512 + u] = act ? f2bf(hn) : (unsigned short)0;
}

// ---------------- W_out f32 -> bf16 ---------------------------------------------
__global__ void __launch_bounds__(256) k_conv(const float* __restrict__ W,
    unsigned short* __restrict__ Wb) {
  size_t i = (size_t)(blockIdx.x * 256 + threadIdx.x) * 4;
  float4 v = *(const float4*)(W + i);
  ushort4v o;
  o.x = f2bf(v.x); o.y = f2bf(v.y); o.z = f2bf(v.z); o.w = f2bf(v.w);
  *(ushort4v*)(Wb + i) = o;
}

// ------ pred[m][n] = Hm[m] . Wb[n] (+ b_out if active); out[(b*32+t)*V + n] -----
__global__ void __launch_bounds__(256) k_gemm(const unsigned short* __restrict__ Hm,
    const unsigned short* __restrict__ Wb, const float* __restrict__ b_out,
    const int* __restrict__ lens, float* __restrict__ out) {
  __shared__ alignas(16) char ldsbuf[32768];  // A 16KB | B 16KB
  char* ldsA = ldsbuf;
  char* ldsB = ldsbuf + 16384;

  int bid = blockIdx.x;
  bid = (bid & 7) * 500 + (bid >> 3);  // XCD swizzle, 4000 % 8 == 0
  int mt = bid / 250, nt = bid % 250;
  int m0 = mt * 128, n0 = nt * 128;
  int tid = threadIdx.x, lane = tid & 63, w = tid >> 6;
  int wm = w >> 1, wn = w & 1;

  f32x4 acc[4][4];
#pragma unroll
  for (int a = 0; a < 4; ++a)
#pragma unroll
    for (int bq = 0; bq < 4; ++bq) acc[a][bq] = (f32x4){0.f, 0.f, 0.f, 0.f};

  const unsigned short* Arow = Hm + (size_t)m0 * 512;
  const unsigned short* Brow = Wb + (size_t)n0 * 512;

  for (int kt = 0; kt < 8; ++kt) {
    int k0 = kt * 64;
    if (kt) __syncthreads();
#pragma unroll
    for (int j = 0; j < 4; ++j) {
      int ci = j * 256 + w * 64 + lane;
      int r = ci >> 3;
      int cph = (ci & 7) << 4;
      int clog = cph ^ ((r & 7) << 4);  // involution: pre-swizzled source
      int ldst = (j * 256 + w * 64) * 16;  // wave-uniform LDS base
      gll16((const char*)(Arow + (size_t)r * 512 + k0) + clog, ldsA + ldst);
      gll16((const char*)(Brow + (size_t)r * 512 + k0) + clog, ldsB + ldst);
    }
    __syncthreads();  // drains vmcnt -> staged data visible
#pragma unroll
    for (int kk = 0; kk < 2; ++kk) {
      short8 af[4], bf[4];
      int cb = kk * 64 + (lane >> 4) * 16;
#pragma unroll
      for (int i = 0; i < 4; ++i) {
        int ar = wm * 64 + i * 16 + (lane & 15);
        af[i] = *(const short8*)(ldsA + ar * 128 + (cb ^ ((ar & 7) << 4)));
        int br = wn * 64 + i * 16 + (lane & 15);
        bf[i] = *(const short8*)(ldsB + br * 128 + (cb ^ ((br & 7) << 4)));
      }
#pragma unroll
      for (int mi = 0; mi < 4; ++mi)
#pragma unroll
        for (int ni = 0; ni < 4; ++ni)
          acc[mi][ni] = __builtin_amdgcn_mfma_f32_16x16x32_bf16(
              af[mi], bf[ni], acc[mi][ni], 0, 0, 0);
    }
  }

#pragma unroll
  for (int mi = 0; mi < 4; ++mi) {
    int mb = m0 + wm * 64 + mi * 16 + ((lane >> 4) << 2);
#pragma unroll
    for (int r = 0; r < 4; ++r) {
      int m = mb + r;
      int t = m >> 6, b = m & 63;
      bool act = lens[b] > t;
      size_t orow = (size_t)(b * 32 + t) * 32000;
#pragma unroll
      for (int ni = 0; ni < 4; ++ni) {
        int n = n0 + wn * 64 + ni * 16 + (lane & 15);
        float v = acc[mi][ni][r];
        if (act) v += b_out[n];
        out[orow + n] = v;
      }
    }
  }
}

extern "C" void kernel_launch(void* const* d_in, const int* in_sizes, int n_in,
                              void* d_out, int out_size, void* d_ws, size_t ws_size,
                              hipStream_t stream) {
  const float* x     = (const float*)d_in[0];
  const int*   ptar  = (const int*)d_in[1];
  const int*   tlen  = (const int*)d_in[2];
  const float* embed = (const float*)d_in[3];
  const float* W_h0  = (const float*)d_in[4];
  const float* b_h0  = (const float*)d_in[5];
  const float* W_c0  = (const float*)d_in[6];
  const float* b_c0  = (const float*)d_in[7];
  const float* W_ih  = (const float*)d_in[8];
  const float* W_hh  = (const float*)d_in[9];
  const float* b_ih  = (const float*)d_in[10];
  const float* b_hh  = (const float*)d_in[11];
  const float* W_out = (const float*)d_in[12];
  const float* b_out = (const float*)d_in[13];
  float* out = (float*)d_out;

  char* ws = (char*)d_ws;
  size_t off = 0;
  auto alloc = [&](size_t bytes) {
    void* p = ws + off;
    off += (bytes + 255) & ~(size_t)255;
    return p;
  };
  unsigned short* Wb = (unsigned short*)alloc(32000ull * 512 * 2);  // 32.75 MB
  unsigned short* Hm = (unsigned short*)alloc(2048ull * 512 * 2);   // 2 MB
  float* xs   = (float*)alloc(64 * 512 * 4);
  float* h0b  = (float*)alloc(64 * 512 * 4);
  float* h1b  = (float*)alloc(64 * 512 * 4);
  float* cbuf = (float*)alloc(64 * 512 * 4);
  float* gx   = (float*)alloc(64 * 2048 * 4);
  int* sidx = (int*)alloc(64 * 4);
  int* lens = (int*)alloc(64 * 4);
  int* tok  = (int*)alloc(2048 * 4);

  // big scratch lives in d_out's prediction region; fully overwritten by k_gemm
  float* GA    = out;                           // 2048*2048 f32
  float* W_ihT = out + 4194304;                 // [768][2048]
  float* W_hhT = out + 4194304 + 1572864;       // [512][2048]
  float* tail  = out + 65536000;                // sorted_indices (as float)

  k_sort<<<1, 256, 0, stream>>>(x, ptar, tlen, sidx, lens, tok, xs, tail);
  k_transpose<<<dim3(24, 64), 256, 0, stream>>>(W_ih, W_ihT, 2048, 768);
  k_transpose<<<dim3(16, 64), 256, 0, stream>>>(W_hh, W_hhT, 2048, 512);
  k_init_hc<<<64, 512, 0, stream>>>(xs, W_h0, b_h0, W_c0, b_c0, h0b, cbuf);
  k_gx<<<dim3(8, 64), 256, 0, stream>>>(xs, W_ihT, b_ih, b_hh, gx);
  k_ga<<<dim3(8, 128), 256, 0, stream>>>(tok, embed, W_ihT, gx, GA);
  k_conv<<<16000, 256, 0, stream>>>(W_out, Wb);

  float* hb[2] = {h0b, h1b};
  for (int t = 0; t < 32; ++t)
    k_step<<<dim3(8, 16), 256, 0, stream>>>(hb[t & 1], hb[(t + 1) & 1], cbuf, GA,
                                            W_hhT, lens, Hm, t);

  k_gemm<<<4000, 256, 0, stream>>>(Hm, Wb, b_out, lens, out);
  (void)in_sizes; (void)n_in; (void)out_size; (void)ws_size;
}

// Round 2
// 448.886 us; speedup vs baseline: 3.1111x; 3.1111x over previous
//
#include <hip/hip_runtime.h>

typedef __attribute__((ext_vector_type(8))) short short8;
typedef __attribute__((ext_vector_type(8))) unsigned short ushort8;
typedef __attribute__((ext_vector_type(4))) float f32x4;
typedef __attribute__((ext_vector_type(4))) unsigned short ushort4v;

#define DEV __device__ __forceinline__

DEV unsigned short f2bf(float f) {
  unsigned int u = __float_as_uint(f);
  u += 0x7fffu + ((u >> 16) & 1u);
  return (unsigned short)(u >> 16);
}
DEV float sigm(float x) { return 1.f / (1.f + __expf(-x)); }
DEV float tanh_(float x) { return 1.f - 2.f / (1.f + __expf(2.f * x)); }

typedef __attribute__((address_space(1))) const void* as1cv;
typedef __attribute__((address_space(3))) void* as3v;
DEV void gll16(const void* g, void* l) {
  __builtin_amdgcn_global_load_lds((as1cv)g, (as3v)l, 16, 0, 0);
}

// ---------------- sort (stable desc argsort of lengths) + gathers ---------------
__global__ void __launch_bounds__(256) k_sort(const float* __restrict__ x,
    const int* __restrict__ ptar, const int* __restrict__ tlen,
    int* __restrict__ sidx, int* __restrict__ lens, int* __restrict__ tok,
    float* __restrict__ xs, float* __restrict__ tail) {
  __shared__ int ss[64];
  int tid = threadIdx.x;
  if (tid < 64) {
    int li = tlen[tid];
    int rank = 0;
    for (int j = 0; j < 64; ++j) {
      int lj = tlen[j];
      rank += (lj > li || (lj == li && j < tid)) ? 1 : 0;
    }
    ss[rank] = tid;
  }
  __syncthreads();
  if (tid < 64) {
    int src = ss[tid];
    sidx[tid] = src;
    lens[tid] = tlen[src] - 1;
    tail[tid] = (float)src;
  }
  __syncthreads();
  for (int idx = tid; idx < 32 * 64; idx += 256) {
    int t = idx >> 6, b = idx & 63;
    tok[idx] = ptar[ss[b] * 33 + t];
  }
  for (int idx = tid; idx < 64 * 512; idx += 256) {
    int b = idx >> 9;
    xs[idx] = x[ss[b] * 512 + (idx & 511)];
  }
}

// -------- fused f32->bf16 conversions: Wpro(3072x512) | Wihb2 | Whb | xsb -------
__global__ void __launch_bounds__(256) k_convmany(
    const float* __restrict__ W_h0, const float* __restrict__ W_c0,
    const float* __restrict__ W_ih, const float* __restrict__ W_hh,
    const float* __restrict__ xs,
    unsigned short* __restrict__ Wpro, unsigned short* __restrict__ Wihb2,
    unsigned short* __restrict__ Whb, unsigned short* __restrict__ xsb) {
  long long g = (long long)(blockIdx.x * 256 + threadIdx.x) * 8;
  const float* src;
  unsigned short* dst;
  if (g < 262144) {                       // W_h0 -> Wpro[0:512]
    src = W_h0 + g; dst = Wpro + g;
  } else if (g < 524288) {                // W_c0 -> Wpro[512:1024]
    long long l = g - 262144; src = W_c0 + l; dst = Wpro + 262144 + l;
  } else if (g < 1572864) {               // W_ih[:, :512] -> Wpro[1024:3072]
    long long l = g - 524288;
    long long r = l >> 9, c = l & 511;
    src = W_ih + r * 768 + c; dst = Wpro + 524288 + l;
  } else if (g < 2097152) {               // W_ih[:, 512:768] -> Wihb2
    long long l = g - 1572864;
    long long r = l >> 8, c = l & 255;
    src = W_ih + r * 768 + 512 + c; dst = Wihb2 + l;
  } else if (g < 3145728) {               // W_hh -> Whb
    long long l = g - 2097152; src = W_hh + l; dst = Whb + l;
  } else {                                // xs -> xsb
    long long l = g - 3145728; src = xs + l; dst = xsb + l;
  }
  float4 v0 = *(const float4*)src, v1 = *(const float4*)(src + 4);
  ushort8 o;
  o[0] = f2bf(v0.x); o[1] = f2bf(v0.y); o[2] = f2bf(v0.z); o[3] = f2bf(v0.w);
  o[4] = f2bf(v1.x); o[5] = f2bf(v1.y); o[6] = f2bf(v1.z); o[7] = f2bf(v1.w);
  *(ushort8*)dst = o;
}

// ---------------- W_out f32 -> bf16 ---------------------------------------------
__global__ void __launch_bounds__(256) k_conv(const float* __restrict__ W,
    unsigned short* __restrict__ Wb) {
  size_t i = (size_t)(blockIdx.x * 256 + threadIdx.x) * 4;
  float4 v = *(const float4*)(W + i);
  ushort4v o;
  o.x = f2bf(v.x); o.y = f2bf(v.y); o.z = f2bf(v.z); o.w = f2bf(v.w);
  *(ushort4v*)(Wb + i) = o;
}

// ---- prologue GEMM: [64x512]x[512x3072] -> h0 (bf16), c0 (f32), gx (f32) -------
__global__ void __launch_bounds__(256) k_pro(const unsigned short* __restrict__ xsb,
    const unsigned short* __restrict__ Wpro, const float* __restrict__ b_h0,
    const float* __restrict__ b_c0, const float* __restrict__ b_ih,
    const float* __restrict__ b_hh, unsigned short* __restrict__ h0b,
    float* __restrict__ c, float* __restrict__ gx) {
  int tid = threadIdx.x, lane = tid & 63, w = tid >> 6;
  int n0 = blockIdx.x * 64 + w * 16;
  int lr = lane & 15, lk = lane >> 4;
  f32x4 acc[4];
#pragma unroll
  for (int i = 0; i < 4; ++i) acc[i] = (f32x4){0.f, 0.f, 0.f, 0.f};
  const unsigned short* B = Wpro + (size_t)(n0 + lr) * 512 + lk * 8;
  const unsigned short* A = xsb + (size_t)lr * 512 + lk * 8;
#pragma unroll
  for (int ks = 0; ks < 16; ++ks) {
    short8 bfr = *(const short8*)(B + ks * 32);
#pragma unroll
    for (int mi = 0; mi < 4; ++mi) {
      short8 af = *(const short8*)(A + mi * 16 * 512 + ks * 32);
      acc[mi] = __builtin_amdgcn_mfma_f32_16x16x32_bf16(af, bfr, acc[mi], 0, 0, 0);
    }
  }
  int n = n0 + lr;
#pragma unroll
  for (int mi = 0; mi < 4; ++mi)
#pragma unroll
    for (int r = 0; r < 4; ++r) {
      int b = mi * 16 + lk * 4 + r;
      float v = acc[mi][r];
      if (n < 512) {
        h0b[b * 512 + n] = f2bf(v + b_h0[n]);
      } else if (n < 1024) {
        int u = n - 512;
        c[b * 512 + u] = v + b_c0[u];
      } else {
        int j = n - 1024;
        gx[(size_t)b * 2048 + j] = v + b_ih[j] + b_hh[j];
      }
    }
}

// ---------------- embedding gather -> bf16 Eb[2048][256] ------------------------
__global__ void __launch_bounds__(256) k_emb(const int* __restrict__ tok,
    const float* __restrict__ embed, unsigned short* __restrict__ Eb) {
  int gid = blockIdx.x * 256 + threadIdx.x;  // 65536
  int row = gid >> 5, c8 = (gid & 31) * 8;
  const float* src = embed + (size_t)tok[row] * 256 + c8;
  float4 v0 = *(const float4*)src, v1 = *(const float4*)(src + 4);
  ushort8 o;
  o[0] = f2bf(v0.x); o[1] = f2bf(v0.y); o[2] = f2bf(v0.z); o[3] = f2bf(v0.w);
  o[4] = f2bf(v1.x); o[5] = f2bf(v1.y); o[6] = f2bf(v1.z); o[7] = f2bf(v1.w);
  *(ushort8*)(Eb + (size_t)row * 256 + c8) = o;
}

// ---- GA[m][j] = Eb[m] . Wihb2[j] + gx[m&63][j]   (2048x2048, K=256) ------------
__global__ void __launch_bounds__(256) k_ga2(const unsigned short* __restrict__ Eb,
    const unsigned short* __restrict__ Wb2, const float* __restrict__ gx,
    float* __restrict__ GA) {
  __shared__ alignas(16) char ldsbuf[32768];
  char* ldsA = ldsbuf;
  char* ldsB = ldsbuf + 16384;
  int bid = blockIdx.x;
  int mt = bid & 15, nt = bid >> 4;
  int m0 = mt * 128, n0 = nt * 128;
  int tid = threadIdx.x, lane = tid & 63, w = tid >> 6;
  int wm = w >> 1, wn = w & 1;
  f32x4 acc[4][4];
#pragma unroll
  for (int a = 0; a < 4; ++a)
#pragma unroll
    for (int bq = 0; bq < 4; ++bq) acc[a][bq] = (f32x4){0.f, 0.f, 0.f, 0.f};
  const unsigned short* Arow = Eb + (size_t)m0 * 256;
  const unsigned short* Brow = Wb2 + (size_t)n0 * 256;
  for (int kt = 0; kt < 4; ++kt) {
    int k0 = kt * 64;
    if (kt) __syncthreads();
#pragma unroll
    for (int j = 0; j < 4; ++j) {
      int ci = j * 256 + w * 64 + lane;
      int r = ci >> 3;
      int clog = ((ci & 7) << 4) ^ ((r & 7) << 4);
      int ldst = (j * 256 + w * 64) * 16;
      gll16((const char*)(Arow + (size_t)r * 256 + k0) + clog, ldsA + ldst);
      gll16((const char*)(Brow + (size_t)r * 256 + k0) + clog, ldsB + ldst);
    }
    __syncthreads();
#pragma unroll
    for (int kk = 0; kk < 2; ++kk) {
      short8 af[4], bf[4];
      int cb = kk * 64 + (lane >> 4) * 16;
#pragma unroll
      for (int i = 0; i < 4; ++i) {
        int ar = wm * 64 + i * 16 + (lane & 15);
        af[i] = *(const short8*)(ldsA + ar * 128 + (cb ^ ((ar & 7) << 4)));
        int br = wn * 64 + i * 16 + (lane & 15);
        bf[i] = *(const short8*)(ldsB + br * 128 + (cb ^ ((br & 7) << 4)));
      }
#pragma unroll
      for (int mi = 0; mi < 4; ++mi)
#pragma unroll
        for (int ni = 0; ni < 4; ++ni)
          acc[mi][ni] = __builtin_amdgcn_mfma_f32_16x16x32_bf16(
              af[mi], bf[ni], acc[mi][ni], 0, 0, 0);
    }
  }
#pragma unroll
  for (int mi = 0; mi < 4; ++mi) {
    int mb = m0 + wm * 64 + mi * 16 + ((lane >> 4) << 2);
#pragma unroll
    for (int r = 0; r < 4; ++r) {
      int m = mb + r;
#pragma unroll
      for (int ni = 0; ni < 4; ++ni) {
        int j = n0 + wn * 64 + ni * 16 + (lane & 15);
        GA[(size_t)m * 2048 + j] = acc[mi][ni][r] + gx[(size_t)(m & 63) * 2048 + j];
      }
    }
  }
}

// ---------------- one LSTM step via MFMA ----------------------------------------
// 64 blocks: mh = bk&1 (32 rows), ug = bk>>1 (16 units). wave = gate.
__global__ void __launch_bounds__(256) k_step2(
    const unsigned short* __restrict__ hin, unsigned short* __restrict__ hout,
    float* __restrict__ c, const float* __restrict__ GA,
    const unsigned short* __restrict__ Whb, const int* __restrict__ lens,
    unsigned short* __restrict__ Hm, int t) {
  __shared__ float Gs[4][32][16];
  int tid = threadIdx.x, lane = tid & 63, g = tid >> 6;
  int bk = blockIdx.x, mh = bk & 1, u0 = (bk >> 1) * 16;
  int lr = lane & 15, lk = lane >> 4;
  f32x4 acc[2];
  acc[0] = (f32x4){0.f, 0.f, 0.f, 0.f};
  acc[1] = (f32x4){0.f, 0.f, 0.f, 0.f};
  const unsigned short* B = Whb + (size_t)(g * 512 + u0 + lr) * 512 + lk * 8;
  const unsigned short* A = hin + (size_t)(mh * 32 + lr) * 512 + lk * 8;
#pragma unroll
  for (int ks = 0; ks < 16; ++ks) {
    short8 bfr = *(const short8*)(B + ks * 32);
    short8 a0 = *(const short8*)(A + ks * 32);
    short8 a1 = *(const short8*)(A + 16 * 512 + ks * 32);
    acc[0] = __builtin_amdgcn_mfma_f32_16x16x32_bf16(a0, bfr, acc[0], 0, 0, 0);
    acc[1] = __builtin_amdgcn_mfma_f32_16x16x32_bf16(a1, bfr, acc[1], 0, 0, 0);
  }
  const float* gab = GA + (size_t)(t * 64 + mh * 32) * 2048 + g * 512 + u0 + lr;
#pragma unroll
  for (int mi = 0; mi < 2; ++mi)
#pragma unroll
    for (int r = 0; r < 4; ++r) {
      int rl = mi * 16 + lk * 4 + r;
      Gs[g][rl][lr] = acc[mi][r] + gab[(size_t)rl * 2048];
    }
  __syncthreads();
#pragma unroll
  for (int cell = tid; cell < 512; cell += 256) {
    int row = cell >> 4, uc = cell & 15;
    int b = mh * 32 + row, u = u0 + uc;
    float fi = Gs[0][row][uc], ff = Gs[1][row][uc];
    float fg = Gs[2][row][uc], fo = Gs[3][row][uc];
    float cold = c[b * 512 + u];
    float cn = sigm(ff) * cold + sigm(fi) * tanh_(fg);
    float hn = sigm(fo) * tanh_(cn);
    bool act = lens[b] > t;
    if (act) c[b * 512 + u] = cn;
    unsigned short hb = f2bf(hn);
    hout[b * 512 + u] = act ? hb : hin[b * 512 + u];
    Hm[((size_t)b * 32 + t) * 512 + u] = act ? hb : (unsigned short)0;
  }
}

// ------ pred[m'][n] = Hm[m'] . Wb[n] (+ b_out if active); m' = b*32+t -----------
__global__ void __launch_bounds__(256) k_gemm(const unsigned short* __restrict__ Hm,
    const unsigned short* __restrict__ Wb, const float* __restrict__ b_out,
    const int* __restrict__ lens, float* __restrict__ out) {
  __shared__ alignas(16) char ldsbuf[32768];
  char* ldsA = ldsbuf;
  char* ldsB = ldsbuf + 16384;
  int bid = blockIdx.x;
  int mt = bid & 15, nt = bid >> 4;  // nt-major: XCDs share one Wb slice
  int m0 = mt * 128, n0 = nt * 128;
  int tid = threadIdx.x, lane = tid & 63, w = tid >> 6;
  int wm = w >> 1, wn = w & 1;
  f32x4 acc[4][4];
#pragma unroll
  for (int a = 0; a < 4; ++a)
#pragma unroll
    for (int bq = 0; bq < 4; ++bq) acc[a][bq] = (f32x4){0.f, 0.f, 0.f, 0.f};
  const unsigned short* Arow = Hm + (size_t)m0 * 512;
  const unsigned short* Brow = Wb + (size_t)n0 * 512;
  for (int kt = 0; kt < 8; ++kt) {
    int k0 = kt * 64;
    if (kt) __syncthreads();
#pragma unroll
    for (int j = 0; j < 4; ++j) {
      int ci = j * 256 + w * 64 + lane;
      int r = ci >> 3;
      int clog = ((ci & 7) << 4) ^ ((r & 7) << 4);
      int ldst = (j * 256 + w * 64) * 16;
      gll16((const char*)(Arow + (size_t)r * 512 + k0) + clog, ldsA + ldst);
      gll16((const char*)(Brow + (size_t)r * 512 + k0) + clog, ldsB + ldst);
    }
    __syncthreads();
#pragma unroll
    for (int kk = 0; kk < 2; ++kk) {
      short8 af[4], bf[4];
      int cb = kk * 64 + (lane >> 4) * 16;
#pragma unroll
      for (int i = 0; i < 4; ++i) {
        int ar = wm * 64 + i * 16 + (lane & 15);
        af[i] = *(const short8*)(ldsA + ar * 128 + (cb ^ ((ar & 7) << 4)));
        int br = wn * 64 + i * 16 + (lane & 15);
        bf[i] = *(const short8*)(ldsB + br * 128 + (cb ^ ((br & 7) << 4)));
      }
#pragma unroll
      for (int mi = 0; mi < 4; ++mi)
#pragma unroll
        for (int ni = 0; ni < 4; ++ni)
          acc[mi][ni] = __builtin_amdgcn_mfma_f32_16x16x32_bf16(
              af[mi], bf[ni], acc[mi][ni], 0, 0, 0);
    }
  }
#pragma unroll
  for (int mi = 0; mi < 4; ++mi) {
    int mb = m0 + wm * 64 + mi * 16 + ((lane >> 4) << 2);
#pragma unroll
    for (int r = 0; r < 4; ++r) {
      int m = mb + r;
      int b = m >> 5, t = m & 31;
      bool act = lens[b] > t;
      size_t orow = (size_t)m * 32000;
#pragma unroll
      for (int ni = 0; ni < 4; ++ni) {
        int n = n0 + wn * 64 + ni * 16 + (lane & 15);
        out[orow + n] = act ? (acc[mi][ni][r] + b_out[n]) : 0.f;
      }
    }
  }
}

extern "C" void kernel_launch(void* const* d_in, const int* in_sizes, int n_in,
                              void* d_out, int out_size, void* d_ws, size_t ws_size,
                              hipStream_t stream) {
  const float* x     = (const float*)d_in[0];
  const int*   ptar  = (const int*)d_in[1];
  const int*   tlen  = (const int*)d_in[2];
  const float* embed = (const float*)d_in[3];
  const float* W_h0  = (const float*)d_in[4];
  const float* b_h0  = (const float*)d_in[5];
  const float* W_c0  = (const float*)d_in[6];
  const float* b_c0  = (const float*)d_in[7];
  const float* W_ih  = (const float*)d_in[8];
  const float* W_hh  = (const float*)d_in[9];
  const float* b_ih  = (const float*)d_in[10];
  const float* b_hh  = (const float*)d_in[11];
  const float* W_out = (const float*)d_in[12];
  const float* b_out = (const float*)d_in[13];
  float* out = (float*)d_out;

  char* ws = (char*)d_ws;
  size_t off = 0;
  auto alloc = [&](size_t bytes) {
    void* p = ws + off;
    off += (bytes + 255) & ~(size_t)255;
    return p;
  };
  unsigned short* Wob = (unsigned short*)alloc(32000ull * 512 * 2);
  unsigned short* Hm  = (unsigned short*)alloc(2048ull * 512 * 2);
  float* xs   = (float*)alloc(64 * 512 * 4);
  unsigned short* h0b = (unsigned short*)alloc(64 * 512 * 2);
  unsigned short* h1b = (unsigned short*)alloc(64 * 512 * 2);
  float* cbuf = (float*)alloc(64 * 512 * 4);
  float* gx   = (float*)alloc(64 * 2048 * 4);
  int* sidx = (int*)alloc(64 * 4);
  int* lens = (int*)alloc(64 * 4);
  int* tok  = (int*)alloc(2048 * 4);

  // scratch in d_out's prediction region (all consumed before k_gemm overwrites)
  float* GA = out;                                             // 2048*2048 f32
  unsigned short* Wpro  = (unsigned short*)(out + 4194304);    // 3072*512 bf16
  unsigned short* Wihb2 = (unsigned short*)(out + 4980736);    // 2048*256 bf16
  unsigned short* Whb   = (unsigned short*)(out + 5242880);    // 2048*512 bf16
  unsigned short* Eb    = (unsigned short*)(out + 5767168);    // 2048*256 bf16
  unsigned short* xsb   = (unsigned short*)(out + 6029312);    // 64*512 bf16
  float* tail = out + 65536000;                                // sorted_indices

  k_sort<<<1, 256, 0, stream>>>(x, ptar, tlen, sidx, lens, tok, xs, tail);
  k_convmany<<<1552, 256, 0, stream>>>(W_h0, W_c0, W_ih, W_hh, xs,
                                       Wpro, Wihb2, Whb, xsb);
  k_conv<<<16000, 256, 0, stream>>>(W_out, Wob);
  k_pro<<<48, 256, 0, stream>>>(xsb, Wpro, b_h0, b_c0, b_ih, b_hh, h0b, cbuf, gx);
  k_emb<<<256, 256, 0, stream>>>(tok, embed, Eb);
  k_ga2<<<256, 256, 0, stream>>>(Eb, Wihb2, gx, GA);

  unsigned short* hb[2] = {h0b, h1b};
  for (int t = 0; t < 32; ++t)
    k_step2<<<64, 256, 0, stream>>>(hb[t & 1], hb[(t + 1) & 1], cbuf, GA, Whb,
                                    lens, Hm, t);

  k_gemm<<<4000, 256, 0, stream>>>(Hm, Wob, b_out, lens, out);
  (void)in_sizes; (void)n_in; (void)out_size; (void)ws_size;
}